// Round 10
// baseline (154.371 us; speedup 1.0000x reference)
//
#include <hip/hip_runtime.h>
#include <math.h>

typedef _Float16 f16x8 __attribute__((ext_vector_type(8)));
typedef _Float16 f16x4 __attribute__((ext_vector_type(4)));
typedef float    f32x16 __attribute__((ext_vector_type(16)));
typedef unsigned int u32;

#define DEVINL __device__ __forceinline__

DEVINL float fast_sigmoid(float x) {
    x = fminf(fmaxf(x, -30.f), 30.f);
    return 1.0f / (1.0f + __expf(-x));
}
DEVINL float fast_tanh(float x) {
    x = fminf(fmaxf(x, -15.f), 15.f);
    float e = __expf(-2.f * x);
    return (1.f - e) / (1.f + e);
}
DEVINL f16x8 f16x8_zero() {
    f16x8 v;
    #pragma unroll
    for (int j = 0; j < 8; ++j) v[j] = (_Float16)0.f;
    return v;
}

#define TKY(t) ((t) < 25 ? (t) / 5 : 2)
#define TKX(t) ((t) < 25 ? (t) % 5 : 2)

// ---------------------------------------------------------------------------
// kT_prep: weight repack + zero-init of hA (2MB) and cfr (4MB). (verified r8)
// ---------------------------------------------------------------------------
__global__ void kT_prep(const float* __restrict__ w1, const float* __restrict__ w2,
                        const float* __restrict__ wx, const float* __restrict__ wh,
                        const float* __restrict__ bx, const float* __restrict__ bh,
                        _Float16* __restrict__ wk1F, _Float16* __restrict__ w2F,
                        _Float16* __restrict__ wxF, _Float16* __restrict__ whF,
                        float* __restrict__ btot,
                        float* __restrict__ cfr, _Float16* __restrict__ hA)
{
    int t = blockIdx.x * 256 + threadIdx.x;
    int stride = gridDim.x * 256;

    for (int i = t; i < 3 * 512; i += stride) {       // wk1F
        int j = i & 7, l = (i >> 3) & 63, q = i >> 9;
        int g = l >> 5, m = l & 31;
        int pr = 2 * q + g, pc = j;
        float v = 0.f;
        if (m < 16) {
            int oc = m >> 2, qy = (m >> 1) & 1, qx = m & 1;
            int ky = pr - qy, kx = pc - qx;
            if ((unsigned)ky < 5u && (unsigned)kx < 5u)
                v = w1[oc * 25 + ky * 5 + kx];
        }
        wk1F[i] = (_Float16)v;
    }
    for (int i = t; i < 12 * 512; i += stride) {      // w2F
        int j = i & 7, l = (i >> 3) & 63, q = i >> 9;
        int g = l >> 5, m = l & 31;
        int k = q * 16 + g * 8 + j;
        int pr = k >> 5, pc = (k >> 2) & 7, ic = k & 3;
        float v = 0.f;
        if (m < 16) {
            int oc = m >> 2, qy = (m >> 1) & 1, qx = m & 1;
            int ky = pr - qy, kx = pc - qx;
            if ((unsigned)ky < 5u && (unsigned)kx < 5u)
                v = w2[(oc * 4 + ic) * 25 + ky * 5 + kx];
        }
        w2F[i] = (_Float16)v;
    }
    for (int i = t; i < 10 * 512; i += stride) {      // wxF
        int j = i & 7, l = (i >> 3) & 63, q = i >> 9;
        int g = l >> 5, m = l & 31;
        int k = q * 16 + g * 8 + j;
        int pr = k >> 5, pc = (k >> 2) & 7, ic = k & 3;
        int og = (m & 3) * 8 + (m >> 2);
        float v = (pr < 5 && pc < 5) ? wx[(og * 4 + ic) * 25 + pr * 5 + pc] : 0.f;
        wxF[i] = (_Float16)v;
    }
    for (int i = t; i < 14 * 512; i += stride) {      // whF (j = ch' order)
        int j = i & 7, l = (i >> 3) & 63, q = i >> 9;
        int g = l >> 5, m = l & 31;
        int og = (m & 3) * 8 + (m >> 2);
        int tap = 2 * q + g;
        int icj = 2 * (j & 3) + (j >> 2);
        float v = (tap < 25) ? wh[(og * 8 + icj) * 25 + tap] : 0.f;
        whF[i] = (_Float16)v;
    }
    if (t < 32) {
        int og = (t & 3) * 8 + (t >> 2);
        btot[t] = bx[og] + bh[og];
    }
    float4 z4 = make_float4(0.f, 0.f, 0.f, 0.f);
    for (int i = t; i < 262144; i += stride) ((float4*)cfr)[i] = z4;  // 4MB
    for (int i = t; i < 131072; i += stride) ((float4*)hA)[i]  = z4;  // 2MB
}

// ---------------------------------------------------------------------------
// k123: FUSED conv1+pool -> conv2+pool -> conv3(4->32), all staging in LDS.
// block = (img f, band of 8 xg-rows). 2048 blocks, 256 thr, 69,056 B LDS.
// FIX vs round 9: sS1 widened to 136 cols (pitch 1088 B == verified k2 tile),
// sS2 widened to 72 cols (pitch 576 B == verified k3 tile). All B-gather
// reads are now in-bounds with staged-zero halos (no row wrap / no reads past
// the shared allocation). Read addressing is byte-identical to k2/k3_mfma.
// ---------------------------------------------------------------------------
__global__ __launch_bounds__(256, 2) void k123(
    const float* __restrict__ obs,
    const _Float16* __restrict__ wk1F, const float* __restrict__ b1,
    const _Float16* __restrict__ w2F, const float* __restrict__ b2,
    const _Float16* __restrict__ wxF, const float* __restrict__ btot,
    _Float16* __restrict__ xg)
{
    __shared__ _Float16 sObs[60 * 264];        // 31,680 B (f16 obs, col+2)
    __shared__ _Float16 sS1[28 * 136 * 4];     // 30,464 B [row][col+2][4ch]
    __shared__ _Float16 sS2[12 * 72 * 4];      //  6,912 B [row][col+2][4ch]
    u32* obsU = (u32*)sObs;
    u32* s1U  = (u32*)sS1;
    u32* s2U  = (u32*)sS2;

    int tid = threadIdx.x;
    int lane = tid & 63, w = tid >> 6, g = lane >> 5;
    int band = blockIdx.x & 7;
    int f = blockIdx.x >> 3;
    int y0 = band << 3;
    const float* in = obs + ((size_t)f << 16);

    // phase 0: zero obs tile + s1/s2 halo cols
    for (int i = tid; i < 60 * 132; i += 256) obsU[i] = 0;
    for (int i = tid; i < 448; i += 256) {     // sS1 cols {0,1,130..135}
        int r = i >> 4, c = (i >> 1) & 7, half = i & 1;
        int col = (c < 2) ? c : 128 + c;
        s1U[r * 272 + col * 2 + half] = 0;
    }
    for (int i = tid; i < 192; i += 256) {     // sS2 cols {0,1,66..71}
        int r = i >> 4, c = (i >> 1) & 7, half = i & 1;
        int col = (c < 2) ? c : 64 + c;
        s2U[r * 144 + col * 2 + half] = 0;
    }
    __syncthreads();

    // phase 1: stage obs rows 4y0-14..4y0+45 as f16 (zero-padded)
    int ob0 = (y0 << 2) - 14;
    for (int i = tid; i < 60 * 64; i += 256) {
        int r = i >> 6, c4 = i & 63;
        int gy = ob0 + r;
        if ((unsigned)gy < 256u) {
            float4 v = *(const float4*)(in + (gy << 8) + (c4 << 2));
            union { _Float16 h[2]; u32 u; } p0, p1;
            p0.h[0] = (_Float16)v.x; p0.h[1] = (_Float16)v.y;
            p1.h[0] = (_Float16)v.z; p1.h[1] = (_Float16)v.w;
            int ui = r * 132 + 1 + 2 * c4;
            obsU[ui] = p0.u; obsU[ui + 1] = p1.u;
        }
    }
    __syncthreads();

    // phase 2: conv1+pool -> sS1 rows 0..27 (global s1 row 2y0-6+s)
    {
        f16x8 wk1[3];
        #pragma unroll
        for (int q = 0; q < 3; ++q)
            wk1[q] = *(const f16x8*)(wk1F + ((size_t)q * 64 + lane) * 8);
        float bA = b1[g], bB = b1[g + 2];
        int s1base = (y0 << 1) - 6;
        #pragma unroll
        for (int i = 0; i < 28; ++i) {
            int tt = w * 28 + i;
            int s = tt >> 2;
            int n = ((tt & 3) << 5) + (lane & 31);
            bool valid = (unsigned)(s1base + s) < 128u;   // wave-uniform

            f32x16 acc;
            #pragma unroll
            for (int r = 0; r < 16; ++r) acc[r] = 0.f;
            #pragma unroll
            for (int q = 0; q < 3; ++q) {
                const u32* p = obsU + (2 * s + 2 * q + g) * 132 + n;
                union { f16x8 v; u32 u[4]; } bb;
                bb.u[0] = p[0]; bb.u[1] = p[1]; bb.u[2] = p[2]; bb.u[3] = p[3];
                acc = __builtin_amdgcn_mfma_f32_32x32x16_f16(wk1[q], bb.v, acc, 0, 0, 0);
            }
            float mA = 0.f, mB = 0.f;
            if (valid) {
                mA = fmaxf(fmaxf(fmaxf(acc[0], acc[1]), fmaxf(acc[2], acc[3])) + bA, 0.f);
                mB = fmaxf(fmaxf(fmaxf(acc[4], acc[5]), fmaxf(acc[6], acc[7])) + bB, 0.f);
            }
            sS1[((s * 136 + n + 2) << 2) + g]     = (_Float16)mA;
            sS1[((s * 136 + n + 2) << 2) + g + 2] = (_Float16)mB;
        }
    }
    __syncthreads();

    // phase 3: conv2+pool -> sS2 rows 0..11 (global s2 row y0-2+r)
    {
        f16x8 wf2[12];
        #pragma unroll
        for (int q = 0; q < 12; ++q)
            wf2[q] = *(const f16x8*)(w2F + ((size_t)q * 64 + lane) * 8);
        float bA = b2[g], bB = b2[g + 2];
        #pragma unroll
        for (int i = 0; i < 6; ++i) {
            int tt = w * 6 + i;
            int r = tt >> 1, hx = tt & 1;
            int px = (hx << 5) + (lane & 31);
            bool valid = (unsigned)(y0 - 2 + r) < 64u;    // wave-uniform

            f32x16 acc;
            #pragma unroll
            for (int q = 0; q < 16; ++q) acc[q] = 0.f;
            int base = 2 * r * 1088 + px * 16 + g * 16;   // == verified k2
            #pragma unroll
            for (int q = 0; q < 12; ++q) {
                f16x8 bv = *(const f16x8*)((const char*)sS1 + base +
                                           ((q >> 1) * 1088 + (q & 1) * 32));
                acc = __builtin_amdgcn_mfma_f32_32x32x16_f16(wf2[q], bv, acc, 0, 0, 0);
            }
            float mA = 0.f, mB = 0.f;
            if (valid) {
                mA = fmaxf(fmaxf(fmaxf(acc[0], acc[1]), fmaxf(acc[2], acc[3])) + bA, 0.f);
                mB = fmaxf(fmaxf(fmaxf(acc[4], acc[5]), fmaxf(acc[6], acc[7])) + bB, 0.f);
            }
            sS2[((r * 72 + px + 2) << 2) + g]     = (_Float16)mA;
            sS2[((r * 72 + px + 2) << 2) + g + 2] = (_Float16)mB;
        }
    }
    __syncthreads();

    // phase 4: conv3 (4->32) -> xg global (fragment layout, pre-biased)
    {
        f16x8 wfx[10];
        #pragma unroll
        for (int q = 0; q < 10; ++q)
            wfx[q] = *(const f16x8*)(wxF + ((size_t)q * 64 + lane) * 8);
        float bsel[16];
        #pragma unroll
        for (int r = 0; r < 16; ++r) {
            int row0 = (r & 3) + 8 * (r >> 2);
            bsel[r] = g ? btot[row0 + 4] : btot[row0];
        }
        #pragma unroll
        for (int i = 0; i < 4; ++i) {
            int tt = (w << 2) + i;
            int ly = tt >> 1, hx = tt & 1;
            int px = (hx << 5) + (lane & 31);

            f32x16 acc;
            #pragma unroll
            for (int q = 0; q < 16; ++q) acc[q] = 0.f;
            int base = ly * 576 + px * 8 + g * 16;        // == verified k3
            #pragma unroll
            for (int q = 0; q < 10; ++q) {
                f16x8 bv = *(const f16x8*)((const char*)sS2 + base +
                                           ((q >> 1) * 576 + (q & 1) * 32));
                acc = __builtin_amdgcn_mfma_f32_32x32x16_f16(wfx[q], bv, acc, 0, 0, 0);
            }
            size_t tl = (size_t)f * 128 + (y0 + ly) * 2 + hx;
            f16x8 lo, hi;
            #pragma unroll
            for (int r = 0; r < 8; ++r) {
                lo[r] = (_Float16)(acc[r] + bsel[r]);
                hi[r] = (_Float16)(acc[r + 8] + bsel[r + 8]);
            }
            _Float16* dst = xg + tl * 1024 + lane * 16;
            *(f16x8*)dst       = lo;
            *(f16x8*)(dst + 8) = hi;
        }
    }
}

// ---------------------------------------------------------------------------
// k4v2: one ConvLSTM step (round-8 verified verbatim).
//  - c in fragment-layout f32 cfr[tl][lane][4], updated in place
//  - h ping-pong f16 [pix][ch'] (ch' = cc+4g), whF j-order matches
//  - xg/c/peephole loads issued BEFORE LDS staging (latency overlap)
// ---------------------------------------------------------------------------
__global__ __launch_bounds__(256, 4) void k4v2(
    const _Float16* __restrict__ xg_t, const _Float16* __restrict__ hprev,
    const _Float16* __restrict__ whF, float* __restrict__ cfr,
    const float* __restrict__ wci, const float* __restrict__ wcf,
    const float* __restrict__ wco, _Float16* __restrict__ hnext,
    float* __restrict__ out_hc, int last)
{
    __shared__ _Float16 lds[6 * 68 * 8];     // pitch 1088 B/row
    int tid = threadIdx.x;
    int lane = tid & 63, w = tid >> 6, g = lane >> 5;
    int b  = blockIdx.x >> 5;
    int y0 = (blockIdx.x & 31) << 1;

    int ly = w >> 1, hx = w & 1;
    int px = hx * 32 + (lane & 31);
    int pix = ((y0 + ly) << 6) + px;
    size_t tl = (size_t)b * 128 + (y0 + ly) * 2 + hx;

    // ---- early independent global loads ----
    const f16x8* xs = (const f16x8*)(xg_t + tl * 1024 + (size_t)lane * 16);
    f16x8 xv0 = xs[0], xv1 = xs[1];
    float4 cv = *(const float4*)(cfr + tl * 256 + lane * 4);
    float pci[4], pcf[4], pco[4];
    #pragma unroll
    for (int cc = 0; cc < 4; ++cc) {
        int ppix = ((2 * cc + g) << 12) + pix;
        pci[cc] = wci[ppix];
        pcf[cc] = wcf[ppix];
        pco[cc] = wco[ppix];
    }
    f16x8 wf[14];
    #pragma unroll
    for (int q = 0; q < 14; ++q)
        wf[q] = *(const f16x8*)(whF + ((size_t)q * 64 + lane) * 8);

    int toffs[14];
    #pragma unroll
    for (int q = 0; q < 14; ++q) {
        int t0 = 2 * q, t1 = 2 * q + 1;
        int o0 = TKY(t0) * 1088 + TKX(t0) * 16;
        int o1 = TKY(t1) * 1088 + TKX(t1) * 16;
        toffs[q] = g ? o1 : o0;
    }

    // ---- stage h tile (rows y0-2..y0+3, cols -2..65) ----
    for (int i = tid; i < 6 * 68; i += 256) {
        int r = i / 68, u = i % 68;
        int gy = y0 - 2 + r;
        int gx = u - 2;
        f16x8 v = f16x8_zero();
        if ((unsigned)gy < 64u && (unsigned)gx < 64u)
            v = *(const f16x8*)(hprev + ((((size_t)b << 12) + (gy << 6) + gx) << 3));
        *(f16x8*)&lds[(r * 68 + u) * 8] = v;
    }
    __syncthreads();

    f32x16 acc;
    #pragma unroll
    for (int r = 0; r < 8; ++r) {
        acc[r]     = (float)xv0[r];
        acc[r + 8] = (float)xv1[r];
    }

    int base = ly * 1088 + px * 16;
    #pragma unroll
    for (int q = 0; q < 14; ++q) {
        f16x8 bv = *(const f16x8*)((const char*)lds + base + toffs[q]);
        acc = __builtin_amdgcn_mfma_f32_32x32x16_f16(wf[q], bv, acc, 0, 0, 0);
    }

    float cvv[4] = {cv.x, cv.y, cv.z, cv.w};
    float cn4[4];
    f16x4 hv;
    #pragma unroll
    for (int cc = 0; cc < 4; ++cc) {
        float c_old = cvv[cc];
        float i_ = fast_sigmoid(acc[4 * cc + 0] + c_old * pci[cc]);
        float f_ = fast_sigmoid(acc[4 * cc + 1] + c_old * pcf[cc]);
        float cn = f_ * c_old + i_ * fast_tanh(acc[4 * cc + 2]);
        float o_ = fast_sigmoid(acc[4 * cc + 3] + cn * pco[cc]);
        float hn = o_ * fast_tanh(cn);
        cn4[cc] = cn;
        hv[cc] = (_Float16)hn;
        if (last) {
            int ch = 2 * cc + g;
            size_t sidx = (((size_t)b * 8 + ch) << 12) + pix;
            out_hc[sidx] = hn;
            out_hc[sidx + 1048576] = cn;
        }
    }
    if (!last) {
        *(float4*)(cfr + tl * 256 + lane * 4) =
            make_float4(cn4[0], cn4[1], cn4[2], cn4[3]);
        *(f16x4*)(hnext + ((((size_t)b << 12) + pix) << 3) + 4 * g) = hv;
    }
}

// ---------------------------------------------------------------------------
extern "C" void kernel_launch(void* const* d_in, const int* in_sizes, int n_in,
                              void* d_out, int out_size, void* d_ws, size_t ws_size,
                              hipStream_t stream)
{
    const float* obs = (const float*)d_in[0];
    const float* w1  = (const float*)d_in[1];
    const float* b1  = (const float*)d_in[2];
    const float* w2  = (const float*)d_in[3];
    const float* b2  = (const float*)d_in[4];
    const float* wx  = (const float*)d_in[5];
    const float* bx  = (const float*)d_in[6];
    const float* wh  = (const float*)d_in[7];
    const float* bh  = (const float*)d_in[8];
    const float* wci = (const float*)d_in[9];
    const float* wcf = (const float*)d_in[10];
    const float* wco = (const float*)d_in[11];

    char* wsb = (char*)d_ws;
    // byte layout:
    //   [0, 67,108,864)             xg f16 [32768 tl][1024]
    //   [67,108,864, 69,206,016)    hA f16
    //   [69,206,016, 71,303,168)    hB f16
    //   [71,303,168, 75,497,472)    cfr f32 [4096 tl][64][4]
    //   [75,497,472, ...)           w2F, wxF, whF, wk1F, btot
    _Float16* xg   = (_Float16*)wsb;
    _Float16* hA   = (_Float16*)(wsb + 67108864);
    _Float16* hB   = (_Float16*)(wsb + 69206016);
    float*    cfr  = (float*)(wsb + 71303168);
    _Float16* w2F  = (_Float16*)(wsb + 75497472);
    _Float16* wxF  = (_Float16*)(wsb + 75509760);
    _Float16* whF  = (_Float16*)(wsb + 75520000);
    _Float16* wk1F = (_Float16*)(wsb + 75534336);
    float*    btot = (float*)(wsb + 75537408);

    kT_prep<<<64, 256, 0, stream>>>(w1, w2, wx, wh, bx, bh,
                                    wk1F, w2F, wxF, whF, btot, cfr, hA);

    k123<<<2048, 256, 0, stream>>>(obs, wk1F, b1, w2F, b2, wxF, btot, xg);

    float* outp = (float*)d_out;
    for (int t = 0; t < 8; ++t) {
        const _Float16* hp = (t & 1) ? hB : hA;
        _Float16*       hn = (t & 1) ? hA : hB;
        k4v2<<<1024, 256, 0, stream>>>(
            xg + (size_t)t * 4194304, hp, whF, cfr,
            wci, wcf, wco, hn, outp, t == 7);
    }
}